// Round 5
// baseline (24879.022 us; speedup 1.0000x reference)
//
#include <hip/hip_runtime.h>
#include <math.h>

// ---------------- problem constants ----------------
constexpr int TT = 256, BB = 16, DD = 512;
constexpr int NTOK = 4096;                 // T*B
constexpr int RTOT = 3456;                 // 768 + 384 + 768 + 1536
constexpr int E1OFF = 768, E2OFF = 1152, E3OFF = 1920;

typedef unsigned long long ull;

// ---------------- workspace layout (bytes) ----------------
constexpr size_t OFF_TSUM  = 0;                                  // 4 f
constexpr size_t OFF_TCNT  = 16;                                 // 4 f
constexpr size_t OFF_CNT   = 32;                                 // 8 ints (XCD claim)
constexpr size_t ZBYTES    = 64;
constexpr size_t OFF_RINGR = 4096;                               // 8*4096*8
constexpr size_t OFF_RING3 = OFF_RINGR + 8ull*4096*8;            // 8*512*8
constexpr size_t OFF_RING2 = OFF_RING3 + 8ull*512*8;             // 8*256*8
constexpr size_t OFF_RING1 = OFF_RING2 + 8ull*256*8;             // 8*128*8
constexpr size_t RING_END  = OFF_RING1 + 8ull*128*8;
constexpr size_t RING_BYTES = RING_END - OFF_RINGR;              // 319488
constexpr size_t OFF_GI   = 327680;
constexpr size_t OFF_HS   = OFF_GI  + (size_t)NTOK*RTOT*4;
constexpr size_t OFF_HA3  = OFF_HS  + (size_t)NTOK*256*4;
constexpr size_t OFF_HA2  = OFF_HA3 + (size_t)NTOK*512*4;
constexpr size_t OFF_HA1  = OFF_HA2 + (size_t)NTOK*256*4;
constexpr size_t OFF_AP   = OFF_HA1 + (size_t)NTOK*128*4;
constexpr size_t OFF_MU   = OFF_AP  + (size_t)NTOK*896*4;
constexpr size_t OFF_RSTD = OFF_MU  + 896*4;

// ================= phase 1: gi = x @ Wih^T + b_ih (all 3456 rows) =================
__global__ __launch_bounds__(256) void gemm1_kernel(
    const float* __restrict__ X,
    const float* __restrict__ wR, const float* __restrict__ w1,
    const float* __restrict__ w2, const float* __restrict__ w3,
    const float* __restrict__ bR, const float* __restrict__ b1,
    const float* __restrict__ b2, const float* __restrict__ b3,
    float* __restrict__ GI)
{
  __shared__ float At[32*64];
  __shared__ float Bt[32*64];
  const int n0 = blockIdx.x * 64;
  const int r0 = blockIdx.y * 64;
  const float* W; const float* bias; int rs;
  if (r0 < 768)       { W = wR; bias = bR; rs = 0; }
  else if (r0 < 1152) { W = w1; bias = b1; rs = 768; }
  else if (r0 < 1920) { W = w2; bias = b2; rs = 1152; }
  else                { W = w3; bias = b3; rs = 1920; }
  const int lr0 = r0 - rs;
  const int tid = threadIdx.x;
  const int lm = tid & 63, lk4 = tid >> 6;
  const int tx = tid & 15, ty = tid >> 4;
  float acc[4][4];
#pragma unroll
  for (int i = 0; i < 4; ++i)
#pragma unroll
    for (int q = 0; q < 4; ++q) acc[i][q] = 0.f;

  for (int kb = 0; kb < 512; kb += 32) {
    const float4 a0 = *(const float4*)(X + (size_t)(n0+lm)*512 + kb + lk4*8);
    const float4 a1 = *(const float4*)(X + (size_t)(n0+lm)*512 + kb + lk4*8 + 4);
    const float4 c0 = *(const float4*)(W + (size_t)(lr0+lm)*512 + kb + lk4*8);
    const float4 c1 = *(const float4*)(W + (size_t)(lr0+lm)*512 + kb + lk4*8 + 4);
    __syncthreads();
    At[(lk4*8+0)*64+lm]=a0.x; At[(lk4*8+1)*64+lm]=a0.y; At[(lk4*8+2)*64+lm]=a0.z; At[(lk4*8+3)*64+lm]=a0.w;
    At[(lk4*8+4)*64+lm]=a1.x; At[(lk4*8+5)*64+lm]=a1.y; At[(lk4*8+6)*64+lm]=a1.z; At[(lk4*8+7)*64+lm]=a1.w;
    Bt[(lk4*8+0)*64+lm]=c0.x; Bt[(lk4*8+1)*64+lm]=c0.y; Bt[(lk4*8+2)*64+lm]=c0.z; Bt[(lk4*8+3)*64+lm]=c0.w;
    Bt[(lk4*8+4)*64+lm]=c1.x; Bt[(lk4*8+5)*64+lm]=c1.y; Bt[(lk4*8+6)*64+lm]=c1.z; Bt[(lk4*8+7)*64+lm]=c1.w;
    __syncthreads();
#pragma unroll
    for (int k = 0; k < 32; ++k) {
      const float4 av = *(const float4*)&At[k*64 + ty*4];
      const float4 bv = *(const float4*)&Bt[k*64 + tx*4];
      acc[0][0]=fmaf(av.x,bv.x,acc[0][0]); acc[0][1]=fmaf(av.x,bv.y,acc[0][1]); acc[0][2]=fmaf(av.x,bv.z,acc[0][2]); acc[0][3]=fmaf(av.x,bv.w,acc[0][3]);
      acc[1][0]=fmaf(av.y,bv.x,acc[1][0]); acc[1][1]=fmaf(av.y,bv.y,acc[1][1]); acc[1][2]=fmaf(av.y,bv.z,acc[1][2]); acc[1][3]=fmaf(av.y,bv.w,acc[1][3]);
      acc[2][0]=fmaf(av.z,bv.x,acc[2][0]); acc[2][1]=fmaf(av.z,bv.y,acc[2][1]); acc[2][2]=fmaf(av.z,bv.z,acc[2][2]); acc[2][3]=fmaf(av.z,bv.w,acc[2][3]);
      acc[3][0]=fmaf(av.w,bv.x,acc[3][0]); acc[3][1]=fmaf(av.w,bv.y,acc[3][1]); acc[3][2]=fmaf(av.w,bv.z,acc[3][2]); acc[3][3]=fmaf(av.w,bv.w,acc[3][3]);
    }
  }
  const float4 bb = *(const float4*)(bias + lr0 + tx*4);
#pragma unroll
  for (int i = 0; i < 4; ++i) {
    float4 o;
    o.x = acc[i][0] + bb.x; o.y = acc[i][1] + bb.y; o.z = acc[i][2] + bb.z; o.w = acc[i][3] + bb.w;
    *(float4*)(GI + (size_t)(n0+ty*4+i)*RTOT + r0 + tx*4) = o;
  }
}

// ================= phase 2: persistent scans (XCD-claimed, barrier-free) =================
struct ScanArgs {
  const float* GI;
  const float* rwhh; const float* rbhh; float* hs;  ull* ringR;
  const float* w1;   const float* b1;   float* ha1; ull* ring1;
  const float* w2;   const float* b2;   float* ha2; ull* ring2;
  const float* w3;   const float* b3;   float* ha3; ull* ring3;
  int* cnt;
};

// Expert scan: OPW outputs/WG, KCN = 512/OPW lanes per output, k-chunk = 16.
// Tagged 8-slot L2 ring; no LDS, no barriers; gi via lane-rotated prefetch.
template<int H, int OPW>
__device__ void expert_scan(const float* __restrict__ GIe, const float* __restrict__ whh,
                            const float* __restrict__ bhh, float* __restrict__ hall,
                            volatile ull* ring, int wg)
{
  constexpr int KCN = 512 / OPW;           // H/KCN == 16
  const int tid = threadIdx.x;
  const int j = tid / KCN, kc = tid % KCN;
  const int jg = wg * OPW + j;
  const int lane = tid & 63;
  const int gbase = lane & ~(KCN - 1);     // group base within wave

  float4 wr[4], wz[4], wn[4];
#pragma unroll
  for (int i4 = 0; i4 < 4; ++i4) {
    const int kk = kc * 16 + i4 * 4;
    wr[i4] = *(const float4*)(whh + (size_t)jg * H + kk);
    wz[i4] = *(const float4*)(whh + (size_t)(H + jg) * H + kk);
    wn[i4] = *(const float4*)(whh + (size_t)(2 * H + jg) * H + kk);
  }
  const float gbr = bhh[jg], gbz = bhh[H + jg], gbn = bhh[2 * H + jg];
  // gi pipeline: lane kc holds gi for steps t == kc (mod KCN); reload after use.
  float pgr, pgz, pgn;
  { const float* g = GIe + (size_t)kc * RTOT;
    pgr = __builtin_nontemporal_load(g + jg);
    pgz = __builtin_nontemporal_load(g + H + jg);
    pgn = __builtin_nontemporal_load(g + 2 * H + jg); }

  for (int t = 0; t < NTOK; ++t) {
    const int sl = t & (KCN - 1);
    const float gr = __shfl(pgr, gbase + sl);
    const float gz = __shfl(pgz, gbase + sl);
    const float gn = __shfl(pgn, gbase + sl);
    if (kc == sl && t + KCN < NTOK) {
      const float* g = GIe + (size_t)(t + KCN) * RTOT;
      pgr = __builtin_nontemporal_load(g + jg);
      pgz = __builtin_nontemporal_load(g + H + jg);
      pgn = __builtin_nontemporal_load(g + 2 * H + jg);
    }
    float pr = 0.f, pz = 0.f, pn = 0.f, hprev = 0.f;
    if (t > 0) {
      volatile const ull* rp = ring + (size_t)((t - 1) & 7) * H;
      const unsigned tg = (unsigned)(t - 1);
      ull hv[16];
#pragma unroll
      for (int m = 0; m < 16; ++m) hv[m] = rp[kc * 16 + m];
      bool bad = true;
      while (bad) {
        bad = false;
#pragma unroll
        for (int m = 0; m < 16; ++m)
          if ((unsigned)(hv[m] >> 32) != tg) { hv[m] = rp[kc * 16 + m]; bad = true; }
      }
      ull hpv = rp[jg];
      while ((unsigned)(hpv >> 32) != tg) hpv = rp[jg];
      hprev = __uint_as_float((unsigned)hpv);
#pragma unroll
      for (int i4 = 0; i4 < 4; ++i4) {
        const float h0 = __uint_as_float((unsigned)hv[i4*4+0]);
        const float h1 = __uint_as_float((unsigned)hv[i4*4+1]);
        const float h2 = __uint_as_float((unsigned)hv[i4*4+2]);
        const float h3 = __uint_as_float((unsigned)hv[i4*4+3]);
        pr = fmaf(wr[i4].x, h0, pr); pr = fmaf(wr[i4].y, h1, pr);
        pr = fmaf(wr[i4].z, h2, pr); pr = fmaf(wr[i4].w, h3, pr);
        pz = fmaf(wz[i4].x, h0, pz); pz = fmaf(wz[i4].y, h1, pz);
        pz = fmaf(wz[i4].z, h2, pz); pz = fmaf(wz[i4].w, h3, pz);
        pn = fmaf(wn[i4].x, h0, pn); pn = fmaf(wn[i4].y, h1, pn);
        pn = fmaf(wn[i4].z, h2, pn); pn = fmaf(wn[i4].w, h3, pn);
      }
#pragma unroll
      for (int off = KCN / 2; off; off >>= 1) {
        pr += __shfl_xor(pr, off); pz += __shfl_xor(pz, off); pn += __shfl_xor(pn, off);
      }
    }
    // all lanes compute the gate redundantly (no divergence, no extra hop)
    const float rg = 1.f / (1.f + expf(-(gr + gbr + pr)));
    const float zg = 1.f / (1.f + expf(-(gz + gbz + pz)));
    const float nn = tanhf(gn + rg * (pn + gbn));
    const float hn = (1.f - zg) * nn + zg * hprev;
    if (kc == 0) {
      ring[(size_t)(t & 7) * H + jg] = ((ull)(unsigned)t << 32) | (ull)__float_as_uint(hn);
      __builtin_nontemporal_store(hn, hall + (size_t)t * H + jg);   // history, off-chain
    }
  }
}

// Router scan: 32 WGs x 512 on one XCD. Wave = one output j (8/WG);
// lane = (kc in [0,16), bq in [0,4)); lane handles batches bq*4..bq*4+3.
__device__ void router_scan(const float* __restrict__ GI, const float* __restrict__ whh,
                            const float* __restrict__ bhh, float* __restrict__ hs,
                            volatile ull* ring, int wg)
{
  const int tid = threadIdx.x;
  const int lane = tid & 63;
  const int j = tid >> 6;                  // [0,8)
  const int kc = lane >> 2;                // [0,16)
  const int bq = lane & 3;                 // [0,4)
  const int jg = wg * 8 + j;
  float4 wr[4], wz[4], wn[4];
#pragma unroll
  for (int i4 = 0; i4 < 4; ++i4) {
    const int kk = kc * 16 + i4 * 4;
    wr[i4] = *(const float4*)(whh + (size_t)jg * 256 + kk);
    wz[i4] = *(const float4*)(whh + (size_t)(256 + jg) * 256 + kk);
    wn[i4] = *(const float4*)(whh + (size_t)(512 + jg) * 256 + kk);
  }
  const float gbr = bhh[jg], gbz = bhh[256 + jg], gbn = bhh[512 + jg];
  float pg[12];                            // gi pipeline, t == kc (mod 16)
#pragma unroll
  for (int i = 0; i < 4; ++i) {
    const float* g = GI + (size_t)(kc * 16 + bq * 4 + i) * RTOT;
    pg[i*3+0] = __builtin_nontemporal_load(g + jg);
    pg[i*3+1] = __builtin_nontemporal_load(g + 256 + jg);
    pg[i*3+2] = __builtin_nontemporal_load(g + 512 + jg);
  }
  for (int t = 0; t < TT; ++t) {
    const int sl = t & 15;
    const int src = sl * 4 + bq;
    float gr[4], gz[4], gn[4];
#pragma unroll
    for (int i = 0; i < 4; ++i) {
      gr[i] = __shfl(pg[i*3+0], src);
      gz[i] = __shfl(pg[i*3+1], src);
      gn[i] = __shfl(pg[i*3+2], src);
    }
    if (kc == sl && t + 16 < TT) {
#pragma unroll
      for (int i = 0; i < 4; ++i) {
        const float* g = GI + (size_t)((t + 16) * 16 + bq * 4 + i) * RTOT;
        pg[i*3+0] = __builtin_nontemporal_load(g + jg);
        pg[i*3+1] = __builtin_nontemporal_load(g + 256 + jg);
        pg[i*3+2] = __builtin_nontemporal_load(g + 512 + jg);
      }
    }
    float ar[4] = {0,0,0,0}, az[4] = {0,0,0,0}, an[4] = {0,0,0,0}, hprev[4] = {0,0,0,0};
    if (t > 0) {
      volatile const ull* rp = ring + (size_t)((t - 1) & 7) * 4096;
      const unsigned tg = (unsigned)(t - 1);
#pragma unroll
      for (int i = 0; i < 4; ++i) {
        const int b = bq * 4 + i;
        ull hv[16];
#pragma unroll
        for (int m = 0; m < 16; ++m) hv[m] = rp[b * 256 + kc * 16 + m];
        bool bad = true;
        while (bad) {
          bad = false;
#pragma unroll
          for (int m = 0; m < 16; ++m)
            if ((unsigned)(hv[m] >> 32) != tg) { hv[m] = rp[b * 256 + kc * 16 + m]; bad = true; }
        }
#pragma unroll
        for (int i4 = 0; i4 < 4; ++i4) {
          const float h0 = __uint_as_float((unsigned)hv[i4*4+0]);
          const float h1 = __uint_as_float((unsigned)hv[i4*4+1]);
          const float h2 = __uint_as_float((unsigned)hv[i4*4+2]);
          const float h3 = __uint_as_float((unsigned)hv[i4*4+3]);
          ar[i] = fmaf(wr[i4].x, h0, ar[i]); ar[i] = fmaf(wr[i4].y, h1, ar[i]);
          ar[i] = fmaf(wr[i4].z, h2, ar[i]); ar[i] = fmaf(wr[i4].w, h3, ar[i]);
          az[i] = fmaf(wz[i4].x, h0, az[i]); az[i] = fmaf(wz[i4].y, h1, az[i]);
          az[i] = fmaf(wz[i4].z, h2, az[i]); az[i] = fmaf(wz[i4].w, h3, az[i]);
          an[i] = fmaf(wn[i4].x, h0, an[i]); an[i] = fmaf(wn[i4].y, h1, an[i]);
          an[i] = fmaf(wn[i4].z, h2, an[i]); an[i] = fmaf(wn[i4].w, h3, an[i]);
        }
      }
#pragma unroll
      for (int i = 0; i < 4; ++i) {
        const int b = bq * 4 + i;
        ull hpv = rp[b * 256 + jg];
        while ((unsigned)(hpv >> 32) != tg) hpv = rp[b * 256 + jg];
        hprev[i] = __uint_as_float((unsigned)hpv);
      }
#pragma unroll
      for (int off = 32; off >= 4; off >>= 1) {
#pragma unroll
        for (int i = 0; i < 4; ++i) {
          ar[i] += __shfl_xor(ar[i], off);
          az[i] += __shfl_xor(az[i], off);
          an[i] += __shfl_xor(an[i], off);
        }
      }
    }
#pragma unroll
    for (int i = 0; i < 4; ++i) {
      const float rg = 1.f / (1.f + expf(-(gr[i] + gbr + ar[i])));
      const float zg = 1.f / (1.f + expf(-(gz[i] + gbz + az[i])));
      const float nn = tanhf(gn[i] + rg * (an[i] + gbn));
      const float hn = (1.f - zg) * nn + zg * hprev[i];
      if (kc == 0) {
        const int b = bq * 4 + i;
        ring[(size_t)(t & 7) * 4096 + b * 256 + jg] =
            ((ull)(unsigned)t << 32) | (ull)__float_as_uint(hn);
        __builtin_nontemporal_store(hn, hs + (size_t)t * 4096 + b * 256 + jg);
      }
    }
  }
}

__global__ __launch_bounds__(512) void scan_kernel(ScanArgs A)
{
  // 81984 B LDS blocker: forces 1 WG/CU (2 WGs would need >160 KiB).
  __shared__ int smem[20496];
  if (threadIdx.x == 0) {
    unsigned x;
    asm volatile("s_getreg_b32 %0, hwreg(HW_REG_XCC_ID)" : "=s"(x));
    const int xcd = (int)(x & 7u);
    smem[0] = xcd;
    smem[1] = atomicAdd(A.cnt + xcd, 1);   // claim rank within my XCD
  }
  __syncthreads();                         // only barrier in the whole kernel
  const int xcd = smem[0], r = smem[1];
  if (xcd == 0)      { if (r < 32) expert_scan<512, 16>(A.GI + E3OFF, A.w3, A.b3, A.ha3, A.ring3, r); }
  else if (xcd == 1) { if (r < 32) router_scan(A.GI, A.rwhh, A.rbhh, A.hs, A.ringR, r); }
  else if (xcd == 2) { if (r < 8)  expert_scan<256, 32>(A.GI + E2OFF, A.w2, A.b2, A.ha2, A.ring2, r); }
  else if (xcd == 3) { if (r < 2)  expert_scan<128, 64>(A.GI + E1OFF, A.w1, A.b1, A.ha1, A.ring1, r); }
}

// ================= phase 3a: router head, softmax, eul/task atomics =================
__global__ __launch_bounds__(256) void router_out_kernel(
    const float* __restrict__ hs, const float* __restrict__ ow, const float* __restrict__ ob,
    const int* __restrict__ tids, float* __restrict__ raw_out,
    float* __restrict__ tsum, float* __restrict__ tcnt)
{
  const int tid = threadIdx.x;
  const int lane = tid & 63, w = tid >> 6;
  const int n = blockIdx.x * 4 + w;
  float s0 = 0.f, s1 = 0.f, s2 = 0.f, s3 = 0.f;
#pragma unroll
  for (int q = 0; q < 4; ++q) {
    const int jj = lane + q * 64;
    float h = hs[(size_t)n * 256 + jj];
    h = h > 0.f ? h : 0.f;
    s0 = fmaf(h, ow[jj], s0);
    s1 = fmaf(h, ow[256 + jj], s1);
    s2 = fmaf(h, ow[512 + jj], s2);
    s3 = fmaf(h, ow[768 + jj], s3);
  }
  for (int off = 32; off; off >>= 1) {
    s0 += __shfl_xor(s0, off); s1 += __shfl_xor(s1, off);
    s2 += __shfl_xor(s2, off); s3 += __shfl_xor(s3, off);
  }
  if (lane == 0) {
    const float l0 = s0 + ob[0], l1 = s1 + ob[1], l2 = s2 + ob[2], l3 = s3 + ob[3];
    const float m = fmaxf(fmaxf(l0, l1), fmaxf(l2, l3));
    const float e0 = expf(l0 - m), e1 = expf(l1 - m), e2 = expf(l2 - m), e3 = expf(l3 - m);
    const float inv = 1.f / (e0 + e1 + e2 + e3);
    float4 rv; rv.x = e0 * inv; rv.y = e1 * inv; rv.z = e2 * inv; rv.w = e3 * inv;
    *(float4*)(raw_out + (size_t)n * 4) = rv;
    const float eul = rv.y * 128.f + rv.z * 256.f + rv.w * 512.f;
    const int tk = tids[n];
    atomicAdd(&tsum[tk], eul);
    atomicAdd(&tcnt[tk], 1.f);
  }
}

// ================= phase 3b: BN stats per column =================
__global__ __launch_bounds__(256) void bn_stats_kernel(
    const float* __restrict__ h1, const float* __restrict__ h2, const float* __restrict__ h3,
    float* __restrict__ mu, float* __restrict__ rstd)
{
  const int c = blockIdx.x;
  const float* hp; int He, hc;
  if (c < 128)      { hp = h1; He = 128; hc = c; }
  else if (c < 384) { hp = h2; He = 256; hc = c - 128; }
  else              { hp = h3; He = 512; hc = c - 384; }
  float s = 0.f, s2 = 0.f;
  for (int r = threadIdx.x; r < NTOK; r += 256) {
    const float v = hp[(size_t)r * He + hc];
    s += v; s2 = fmaf(v, v, s2);
  }
  for (int off = 32; off; off >>= 1) { s += __shfl_xor(s, off); s2 += __shfl_xor(s2, off); }
  __shared__ float red[8];
  const int lane = threadIdx.x & 63, w = threadIdx.x >> 6;
  if (lane == 0) { red[w] = s; red[4 + w] = s2; }
  __syncthreads();
  if (threadIdx.x == 0) {
    const float S = red[0] + red[1] + red[2] + red[3];
    const float S2 = red[4] + red[5] + red[6] + red[7];
    const float m = S * (1.f / 4096.f);
    float v = S2 * (1.f / 4096.f) - m * m;
    v = v > 0.f ? v : 0.f;
    mu[c] = m;
    rstd[c] = 1.f / sqrtf(v + 1e-5f);
  }
}

// ================= phase 3c: A' = gate * relu(bn(h)); plus task losses =================
__global__ __launch_bounds__(256) void aprime_kernel(
    const float* __restrict__ h1, const float* __restrict__ h2, const float* __restrict__ h3,
    const float* __restrict__ g1, const float* __restrict__ be1,
    const float* __restrict__ g2, const float* __restrict__ be2,
    const float* __restrict__ g3, const float* __restrict__ be3,
    const float* __restrict__ mu, const float* __restrict__ rstd,
    const float* __restrict__ raw, float* __restrict__ Ap,
    const float* __restrict__ tsum, const float* __restrict__ tcnt, float* __restrict__ tl_out)
{
  if (blockIdx.x == 4096) {
    if (threadIdx.x < 4) tl_out[threadIdx.x] = tsum[threadIdx.x] / tcnt[threadIdx.x];
    return;
  }
  const int n = blockIdx.x;
  for (int c = threadIdx.x; c < 896; c += 256) {
    const float* hp; const float* gg; const float* bb; int He, hc, e;
    if (c < 128)      { hp = h1; gg = g1; bb = be1; He = 128; hc = c;       e = 1; }
    else if (c < 384) { hp = h2; gg = g2; bb = be2; He = 256; hc = c - 128; e = 2; }
    else              { hp = h3; gg = g3; bb = be3; He = 512; hc = c - 384; e = 3; }
    const float h = hp[(size_t)n * He + hc];
    float v = (h - mu[c]) * rstd[c] * gg[hc] + bb[hc];
    v = v > 0.f ? v : 0.f;
    Ap[(size_t)n * 896 + c] = raw[(size_t)n * 4 + e] * v;
  }
}

// ================= phase 4: out = A' @ OWc^T + gated biases + g0*x =================
__global__ __launch_bounds__(256) void out_gemm_kernel(
    const float* __restrict__ Ap,
    const float* __restrict__ ow1, const float* __restrict__ ow2, const float* __restrict__ ow3,
    const float* __restrict__ ob1, const float* __restrict__ ob2, const float* __restrict__ ob3,
    const float* __restrict__ X, const float* __restrict__ raw, float* __restrict__ out)
{
  __shared__ float At[32*64];
  __shared__ float Bt[32*64];
  const int n0 = blockIdx.x * 64;
  const int d0 = blockIdx.y * 64;
  const int tid = threadIdx.x;
  const int lm = tid & 63, lk4 = tid >> 6;
  const int tx = tid & 15, ty = tid >> 4;
  float acc[4][4];
#pragma unroll
  for (int i = 0; i < 4; ++i)
#pragma unroll
    for (int q = 0; q < 4; ++q) acc[i][q] = 0.f;

  for (int kb = 0; kb < 896; kb += 32) {
    const float* W; int He, ko;
    if (kb < 128)      { W = ow1; He = 128; ko = 0; }
    else if (kb < 384) { W = ow2; He = 256; ko = 128; }
    else               { W = ow3; He = 512; ko = 384; }
    const float4 a0 = *(const float4*)(Ap + (size_t)(n0+lm)*896 + kb + lk4*8);
    const float4 a1 = *(const float4*)(Ap + (size_t)(n0+lm)*896 + kb + lk4*8 + 4);
    const float4 c0 = *(const float4*)(W + (size_t)(d0+lm)*He + (kb - ko) + lk4*8);
    const float4 c1 = *(const float4*)(W + (size_t)(d0+lm)*He + (kb - ko) + lk4*8 + 4);
    __syncthreads();
    At[(lk4*8+0)*64+lm]=a0.x; At[(lk4*8+1)*64+lm]=a0.y; At[(lk4*8+2)*64+lm]=a0.z; At[(lk4*8+3)*64+lm]=a0.w;
    At[(lk4*8+4)*64+lm]=a1.x; At[(lk4*8+5)*64+lm]=a1.y; At[(lk4*8+6)*64+lm]=a1.z; At[(lk4*8+7)*64+lm]=a1.w;
    Bt[(lk4*8+0)*64+lm]=c0.x; Bt[(lk4*8+1)*64+lm]=c0.y; Bt[(lk4*8+2)*64+lm]=c0.z; Bt[(lk4*8+3)*64+lm]=c0.w;
    Bt[(lk4*8+4)*64+lm]=c1.x; Bt[(lk4*8+5)*64+lm]=c1.y; Bt[(lk4*8+6)*64+lm]=c1.z; Bt[(lk4*8+7)*64+lm]=c1.w;
    __syncthreads();
#pragma unroll
    for (int k = 0; k < 32; ++k) {
      const float4 av = *(const float4*)&At[k*64 + ty*4];
      const float4 bv = *(const float4*)&Bt[k*64 + tx*4];
      acc[0][0]=fmaf(av.x,bv.x,acc[0][0]); acc[0][1]=fmaf(av.x,bv.y,acc[0][1]); acc[0][2]=fmaf(av.x,bv.z,acc[0][2]); acc[0][3]=fmaf(av.x,bv.w,acc[0][3]);
      acc[1][0]=fmaf(av.y,bv.x,acc[1][0]); acc[1][1]=fmaf(av.y,bv.y,acc[1][1]); acc[1][2]=fmaf(av.y,bv.z,acc[1][2]); acc[1][3]=fmaf(av.y,bv.w,acc[1][3]);
      acc[2][0]=fmaf(av.z,bv.x,acc[2][0]); acc[2][1]=fmaf(av.z,bv.y,acc[2][1]); acc[2][2]=fmaf(av.z,bv.z,acc[2][2]); acc[2][3]=fmaf(av.z,bv.w,acc[2][3]);
      acc[3][0]=fmaf(av.w,bv.x,acc[3][0]); acc[3][1]=fmaf(av.w,bv.y,acc[3][1]); acc[3][2]=fmaf(av.w,bv.z,acc[3][2]); acc[3][3]=fmaf(av.w,bv.w,acc[3][3]);
    }
  }
#pragma unroll
  for (int i = 0; i < 4; ++i) {
    const int n = n0 + ty * 4 + i;
    const float4 g  = *(const float4*)(raw + (size_t)n * 4);
    const float4 xv = *(const float4*)(X + (size_t)n * 512 + d0 + tx * 4);
    const float4 o1 = *(const float4*)(ob1 + d0 + tx * 4);
    const float4 o2 = *(const float4*)(ob2 + d0 + tx * 4);
    const float4 o3 = *(const float4*)(ob3 + d0 + tx * 4);
    float4 o;
    o.x = acc[i][0] + g.x*xv.x + g.y*o1.x + g.z*o2.x + g.w*o3.x;
    o.y = acc[i][1] + g.x*xv.y + g.y*o1.y + g.z*o2.y + g.w*o3.y;
    o.z = acc[i][2] + g.x*xv.z + g.y*o1.z + g.z*o2.z + g.w*o3.z;
    o.w = acc[i][3] + g.x*xv.w + g.y*o1.w + g.z*o2.w + g.w*o3.w;
    *(float4*)(out + (size_t)n * 512 + d0 + tx * 4) = o;
  }
}

// ================= host =================
extern "C" void kernel_launch(void* const* d_in, const int* in_sizes, int n_in,
                              void* d_out, int out_size, void* d_ws, size_t ws_size,
                              hipStream_t stream) {
  const float* x    = (const float*)d_in[0];
  const int*   tids = (const int*)d_in[1];
  const float* rwih = (const float*)d_in[2];
  const float* rwhh = (const float*)d_in[3];
  const float* rbih = (const float*)d_in[4];
  const float* rbhh = (const float*)d_in[5];
  const float* row  = (const float*)d_in[6];
  const float* rob  = (const float*)d_in[7];
  const float* w1ih = (const float*)d_in[8];
  const float* w1hh = (const float*)d_in[9];
  const float* b1ih = (const float*)d_in[10];
  const float* b1hh = (const float*)d_in[11];
  const float* bn1g = (const float*)d_in[12];
  const float* bn1b = (const float*)d_in[13];
  const float* ow1  = (const float*)d_in[14];
  const float* ob1  = (const float*)d_in[15];
  const float* w2ih = (const float*)d_in[16];
  const float* w2hh = (const float*)d_in[17];
  const float* b2ih = (const float*)d_in[18];
  const float* b2hh = (const float*)d_in[19];
  const float* bn2g = (const float*)d_in[20];
  const float* bn2b = (const float*)d_in[21];
  const float* ow2  = (const float*)d_in[22];
  const float* ob2  = (const float*)d_in[23];
  const float* w3ih = (const float*)d_in[24];
  const float* w3hh = (const float*)d_in[25];
  const float* b3ih = (const float*)d_in[26];
  const float* b3hh = (const float*)d_in[27];
  const float* bn3g = (const float*)d_in[28];
  const float* bn3b = (const float*)d_in[29];
  const float* ow3  = (const float*)d_in[30];
  const float* ob3  = (const float*)d_in[31];

  char* ws = (char*)d_ws;
  float* tsum  = (float*)(ws + OFF_TSUM);
  float* tcnt  = (float*)(ws + OFF_TCNT);
  int*   cnt   = (int*)(ws + OFF_CNT);
  ull*   ringR = (ull*)(ws + OFF_RINGR);
  ull*   ring3 = (ull*)(ws + OFF_RING3);
  ull*   ring2 = (ull*)(ws + OFF_RING2);
  ull*   ring1 = (ull*)(ws + OFF_RING1);
  float* GI    = (float*)(ws + OFF_GI);
  float* hs    = (float*)(ws + OFF_HS);
  float* ha3   = (float*)(ws + OFF_HA3);
  float* ha2   = (float*)(ws + OFF_HA2);
  float* ha1   = (float*)(ws + OFF_HA1);
  float* Ap    = (float*)(ws + OFF_AP);
  float* mu    = (float*)(ws + OFF_MU);
  float* rstd  = (float*)(ws + OFF_RSTD);

  float* outp = (float*)d_out;
  float* rawp = outp + (size_t)NTOK * DD;
  float* tlp  = rawp + (size_t)NTOK * 4;

  // zero claim/task accumulators; poison the tagged rings (tag 0xAAAAAAAA != any t)
  hipMemsetAsync(ws, 0, ZBYTES, stream);
  hipMemsetAsync(ws + OFF_RINGR, 0xAA, RING_BYTES, stream);

  // phase 1: input projections for router + all experts
  gemm1_kernel<<<dim3(64, 54), 256, 0, stream>>>(x, rwih, w1ih, w2ih, w3ih,
                                                 rbih, b1ih, b2ih, b3ih, GI);

  // phase 2: barrier-free XCD-claimed scans (tagged L2 rings, 1 WG/CU)
  ScanArgs sa;
  sa.GI = GI;
  sa.rwhh = rwhh; sa.rbhh = rbhh; sa.hs = hs;  sa.ringR = ringR;
  sa.w1 = w1hh;   sa.b1 = b1hh;   sa.ha1 = ha1; sa.ring1 = ring1;
  sa.w2 = w2hh;   sa.b2 = b2hh;   sa.ha2 = ha2; sa.ring2 = ring2;
  sa.w3 = w3hh;   sa.b3 = b3hh;   sa.ha3 = ha3; sa.ring3 = ring3;
  sa.cnt = cnt;
  scan_kernel<<<dim3(768), dim3(512), 0, stream>>>(sa);

  // phase 3: router head + task-loss atomics; BN stats; A' build (+ task losses)
  router_out_kernel<<<dim3(1024), 256, 0, stream>>>(hs, row, rob, tids, rawp, tsum, tcnt);
  bn_stats_kernel<<<dim3(896), 256, 0, stream>>>(ha1, ha2, ha3, mu, rstd);
  aprime_kernel<<<dim3(4097), 256, 0, stream>>>(ha1, ha2, ha3, bn1g, bn1b, bn2g, bn2b,
                                                bn3g, bn3b, mu, rstd, rawp, Ap,
                                                tsum, tcnt, tlp);

  // phase 4: gated expert-output GEMM + identity expert + gated biases
  out_gemm_kernel<<<dim3(64, 8), 256, 0, stream>>>(Ap, ow1, ow2, ow3, ob1, ob2, ob3,
                                                   x, rawp, outp);
}